// Round 12
// baseline (164.045 us; speedup 1.0000x reference)
//
#include <hip/hip_runtime.h>

#define NP   16
#define EDIM 64
#define HH   8
#define BB   2
#define LL   2048
#define SS   2048
#define NQT  32
#define NPAIR 16
#define LDP  72            // LDS row stride in bf16 (64 + 8 pad)
#define NW   8             // waves per attn block

typedef __attribute__((ext_vector_type(8))) short bf16x8;
typedef __attribute__((ext_vector_type(4))) float f32x4;

__device__ __forceinline__ float bf2f(unsigned int u) {
    union { unsigned int i; float f; } x; x.i = u << 16; return x.f;
}
__device__ __forceinline__ unsigned short f2bf(float f) {
    union { float ff; unsigned int i; } x; x.ff = f;
    unsigned int r = x.i + 0x7fffu + ((x.i >> 16) & 1u);
    return (unsigned short)(r >> 16);
}
__device__ __forceinline__ unsigned int pk2(float a, float b) {
    return (unsigned int)f2bf(a) | ((unsigned int)f2bf(b) << 16);
}
__device__ __forceinline__ unsigned int tpk2(float a, float b) {   // truncate-pack
    union { float f; unsigned int i; } xa, xb; xa.f = a; xb.f = b;
    return (xa.i >> 16) | (xb.i & 0xffff0000u);
}

// 16 fp32 (global) -> 16 bf16 (LDS), scaled
__device__ __forceinline__ void stage16s(const float* __restrict__ g, unsigned short* l, float sc) {
    const float4* gp = (const float4*)g;
    float4 v0 = gp[0], v1 = gp[1], v2 = gp[2], v3 = gp[3];
    uint4 w0, w1;
    w0.x = pk2(v0.x * sc, v0.y * sc); w0.y = pk2(v0.z * sc, v0.w * sc);
    w0.z = pk2(v1.x * sc, v1.y * sc); w0.w = pk2(v1.z * sc, v1.w * sc);
    w1.x = pk2(v2.x * sc, v2.y * sc); w1.y = pk2(v2.z * sc, v2.w * sc);
    w1.z = pk2(v3.x * sc, v3.y * sc); w1.w = pk2(v3.z * sc, v3.w * sc);
    ((uint4*)l)[0] = w0; ((uint4*)l)[1] = w1;
}

#define INV4PI 0.07957747154594767f

// ---------------------------------------------------------------------------
// Kernel 1: quantum encoding. 4 THREADS PER TOKEN (quad = one token):
// each thread does a 16-e slice of the angle GEMV (quad shfl_xor reduce),
// redundant circuit+measure, and a 16-e slice of the out-GEMV. Weights read
// directly from global (L1-resident). No LDS, no barriers. 8 waves/CU.
// Outputs: qevb (bf16 [B,H,E,S]) + Kb (bf16 [B,H,S,E]).
// ---------------------------------------------------------------------------
__global__ __launch_bounds__(256)
void qev4_kernel(const float* __restrict__ values,  // [B,S,H,E]
                 const float* __restrict__ key,     // [B,S,H,E]
                 const float* __restrict__ Wang, const float* __restrict__ bang,
                 const float* __restrict__ Wout, const float* __restrict__ bout,
                 unsigned short* __restrict__ qevb, // [B,H,E,S]
                 unsigned short* __restrict__ Kb)   // [B,H,S,E]
{
    const int tid   = threadIdx.x;
    const int s0    = blockIdx.x * 64;
    const int h     = blockIdx.y;
    const int b     = blockIdx.z;
    const int token = s0 + (tid >> 2);     // 64 tokens per block
    const int p4    = tid & 3;             // my 16-e slice

    // ---- my quarter of the value row ----
    const float* vptr = values + ((size_t)(b * SS + token) * HH + h) * EDIM + p4 * 16;
    float4 vv[4];
#pragma unroll
    for (int c = 0; c < 4; c++) vv[c] = ((const float4*)vptr)[c];

    // ---- angles: partial over my 16 e's, quad-reduce, add bias ----
    float ang[NP];
#pragma unroll
    for (int p = 0; p < NP; p++) {
        const float4* wp = (const float4*)(Wang + p * EDIM + p4 * 16);
        float a = 0.f;
#pragma unroll
        for (int c = 0; c < 4; c++) {
            float4 w = wp[c];
            a = fmaf(w.x, vv[c].x, a);
            a = fmaf(w.y, vv[c].y, a);
            a = fmaf(w.z, vv[c].z, a);
            a = fmaf(w.w, vv[c].w, a);
        }
        a += __shfl_xor(a, 1, 64);
        a += __shfl_xor(a, 2, 64);
        ang[p] = a + bang[p];
    }

    float sc[NP], cc[NP];
#pragma unroll
    for (int p = 0; p < NP; p++) {
        float u = ang[p] * INV4PI;
        sc[p] = __builtin_amdgcn_sinf(u);
        cc[p] = __builtin_amdgcn_cosf(u);
    }

    // ---- 4-qubit circuit (redundant per quad-thread; identical math) ----
    float sr[16], si[16];
#pragma unroll
    for (int i = 0; i < 16; i++) { sr[i] = 0.f; si[i] = 0.f; }
    sr[0] = 1.f;

    auto RY = [&](int w, float s, float c) {
        const int bit = 8 >> w;
#pragma unroll
        for (int i = 0; i < 16; i++) {
            if (!(i & bit)) {
                const int j = i | bit;
                float a0r = sr[i], a0i = si[i], a1r = sr[j], a1i = si[j];
                sr[i] = c * a0r - s * a1r;  si[i] = c * a0i - s * a1i;
                sr[j] = s * a0r + c * a1r;  si[j] = s * a0i + c * a1i;
            }
        }
    };
    auto CRX = [&](int cw, int tw, float s, float c) {
        const int cbit = 8 >> cw, tbit = 8 >> tw;
#pragma unroll
        for (int i = 0; i < 16; i++) {
            if ((i & cbit) && !(i & tbit)) {
                const int j = i | tbit;
                float a0r = sr[i], a0i = si[i], a1r = sr[j], a1i = si[j];
                sr[i] =  c * a0r + s * a1i;  si[i] =  c * a0i - s * a1r;
                sr[j] =  s * a0i + c * a1r;  si[j] = -s * a0r + c * a1i;
            }
        }
    };

    RY(0, sc[0], cc[0]); RY(1, sc[1], cc[1]); RY(2, sc[2], cc[2]); RY(3, sc[3], cc[3]);
    CRX(3, 0, sc[4], cc[4]); CRX(2, 3, sc[5], cc[5]); CRX(1, 2, sc[6], cc[6]); CRX(0, 1, sc[7], cc[7]);
    RY(0, sc[8], cc[8]); RY(1, sc[9], cc[9]); RY(2, sc[10], cc[10]); RY(3, sc[11], cc[11]);
    CRX(3, 2, sc[12], cc[12]); CRX(0, 3, sc[13], cc[13]); CRX(1, 0, sc[14], cc[14]); CRX(2, 1, sc[15], cc[15]);

    float meas[12];
#pragma unroll
    for (int w = 0; w < 4; w++) {
        const int bit = 8 >> w;
        float pr = 0.f, pi = 0.f, z = 0.f;
#pragma unroll
        for (int i = 0; i < 16; i++) {
            if (!(i & bit)) {
                const int j = i | bit;
                pr += sr[i] * sr[j] + si[i] * si[j];
                pi += sr[i] * si[j] - si[i] * sr[j];
                z  += sr[i] * sr[i] + si[i] * si[i] - sr[j] * sr[j] - si[j] * si[j];
            }
        }
        meas[w] = 2.f * pr; meas[4 + w] = 2.f * pi; meas[8 + w] = z;
    }

    // ---- out-GEMV: my 16 e's (Wout rows are 48 B = 16B-aligned) ----
    unsigned short* ob = qevb + ((size_t)(b * HH + h) * EDIM) * SS + token;
    const float4* bo4 = (const float4*)(bout + p4 * 16);
    float4 bo[4] = { bo4[0], bo4[1], bo4[2], bo4[3] };
#pragma unroll
    for (int j = 0; j < 16; j++) {
        const int e = p4 * 16 + j;
        const float4* wr = (const float4*)(Wout + e * 12);
        float4 w0 = wr[0], w1 = wr[1], w2 = wr[2];
        float a = ((const float*)bo)[j];
        a = fmaf(meas[0], w0.x, a);  a = fmaf(meas[1],  w0.y, a);
        a = fmaf(meas[2], w0.z, a);  a = fmaf(meas[3],  w0.w, a);
        a = fmaf(meas[4], w1.x, a);  a = fmaf(meas[5],  w1.y, a);
        a = fmaf(meas[6], w1.z, a);  a = fmaf(meas[7],  w1.w, a);
        a = fmaf(meas[8], w2.x, a);  a = fmaf(meas[9],  w2.y, a);
        a = fmaf(meas[10], w2.z, a); a = fmaf(meas[11], w2.w, a);
        ob[(size_t)e * SS] = f2bf(a);
    }

    // ---- K conversion (coalesced 512B writes; 4 iters at 256 threads) ----
    const float* ks = key + ((size_t)b * SS * HH + h) * EDIM;
    unsigned short* kd = Kb + ((size_t)(b * HH + h) * SS + s0) * EDIM;
#pragma unroll
    for (int i = 0; i < 4; i++) {
        const int u   = i * 256 + tid;     // uint2 unit 0..1023
        const int row = u >> 4;
        const int ch  = u & 15;
        float4 v = *(const float4*)(ks + (size_t)(s0 + row) * HH * EDIM + ch * 4);
        uint2 w2; w2.x = pk2(v.x, v.y); w2.y = pk2(v.z, v.w);
        *(uint2*)&kd[row * EDIM + ch * 4] = w2;
    }
}

// ---------------------------------------------------------------------------
// Kernel 2: wave-owned-tile MFMA attention, 8 waves/block (512 thr), one
// causal pair (qt = bx, 31-bx). Wave w owns tiles t === w (mod 8), all 64
// q-rows (no-max softmax partials are exactly additive). Barrier-free
// K-loop; register prefetch one own-tile ahead. 91 KB dynamic LDS:
// Qs + 8 per-wave P/O-partial buffers + Lbuf.
// ---------------------------------------------------------------------------
__global__ __launch_bounds__(512, 1)
void attn7_kernel(const float* __restrict__ qry,            // [B,L,H,E] fp32
                  const unsigned short* __restrict__ Kb,    // [B,H,S,E] bf16
                  const unsigned short* __restrict__ Vb,    // [B,H,E,S] bf16
                  float* __restrict__ out)                  // [B,L,H,E] fp32
{
    extern __shared__ unsigned short smem[];
    unsigned short* Qs = smem;                       // 64*LDP
    unsigned short* Pq = smem + 64 * LDP;            // NW * 64*LDP
    float* Lbuf = (float*)(smem + (1 + NW) * 64 * LDP);   // [NW*4][64]

    const int tid  = threadIdx.x;
    const int bx   = blockIdx.x;
    const int h    = blockIdx.y;
    const int b    = blockIdx.z;
    const int w    = tid >> 6;       // 0..7
    const int lane = tid & 63;
    const int ml   = lane & 15;
    const int quad = lane >> 4;

    const unsigned short* kbase = Kb + (size_t)(b * HH + h) * SS * EDIM;
    const unsigned short* vbase = Vb + (size_t)(b * HH + h) * EDIM * SS;
    unsigned short* Pw = Pq + w * 64 * LDP;

    for (int pass = 0; pass < 2; ++pass) {
        const int qt = pass ? (NQT - 1 - bx) : bx;
        const int q0 = qt * 64;

        __syncthreads();   // prev pass fully done with Qs/Pq
        if (tid < 256) {
            const int srow = tid >> 2, sch = tid & 3;
            stage16s(qry + (((size_t)b * LL + q0 + srow) * HH + h) * EDIM + sch * 16,
                     &Qs[srow * LDP + sch * 16], 0.125f);
        }
        __syncthreads();

        // Q B-fragments (rows = q), loop-invariant
        bf16x8 bq[4][2];
#pragma unroll
        for (int ntq = 0; ntq < 4; ntq++) {
            bq[ntq][0] = *(const bf16x8*)&Qs[(16 * ntq + ml) * LDP + quad * 8];
            bq[ntq][1] = *(const bf16x8*)&Qs[(16 * ntq + ml) * LDP + quad * 8 + 32];
        }

        f32x4 oaccT[4][4];    // [mte][ntq]: O^T[e][q]
        float lacc[4] = {0.f, 0.f, 0.f, 0.f};
#pragma unroll
        for (int i = 0; i < 4; i++)
#pragma unroll
            for (int j = 0; j < 4; j++) oaccT[i][j] = (f32x4)(0.f);

        int t = w;
        uint4 kc[8], vc[8];
        if (t <= qt) {
#pragma unroll
            for (int f = 0; f < 8; f++) {
                const int mt = f >> 1, hf = f & 1;
                kc[f] = *(const uint4*)(kbase + (size_t)(t * 64 + 16 * mt + ml) * EDIM + quad * 8 + 32 * hf);
                vc[f] = *(const uint4*)(vbase + (size_t)(16 * mt + ml) * SS + t * 64 + quad * 8 + 32 * hf);
            }
        }

        for (; t <= qt; t += NW) {
            uint4 kn[8], vn[8];
            const bool more = (t + NW <= qt);
            if (more) {
#pragma unroll
                for (int f = 0; f < 8; f++) {
                    const int mt = f >> 1, hf = f & 1;
                    kn[f] = *(const uint4*)(kbase + (size_t)((t + NW) * 64 + 16 * mt + ml) * EDIM + quad * 8 + 32 * hf);
                    vn[f] = *(const uint4*)(vbase + (size_t)(16 * mt + ml) * SS + (t + NW) * 64 + quad * 8 + 32 * hf);
                }
            }
            const bool diag = (t == qt);

            // ---- S^T = K*Q^T, exp, pack into Pw[q][s] ----
#pragma unroll
            for (int mts = 0; mts < 4; mts++)
#pragma unroll
                for (int ntq = 0; ntq < 4; ntq++) {
                    f32x4 s = __builtin_amdgcn_mfma_f32_16x16x32_bf16(
                        *(const bf16x8*)&kc[2 * mts], bq[ntq][0], (f32x4)(0.f), 0, 0, 0);
                    s = __builtin_amdgcn_mfma_f32_16x16x32_bf16(
                        *(const bf16x8*)&kc[2 * mts + 1], bq[ntq][1], s, 0, 0, 0);
                    float p0 = __expf(s[0]), p1 = __expf(s[1]), p2 = __expf(s[2]), p3 = __expf(s[3]);
                    if (diag) {
                        const int sbase = 16 * mts + 4 * quad, qcol = 16 * ntq + ml;
                        if (sbase + 0 > qcol) p0 = 0.f;
                        if (sbase + 1 > qcol) p1 = 0.f;
                        if (sbase + 2 > qcol) p2 = 0.f;
                        if (sbase + 3 > qcol) p3 = 0.f;
                    }
                    lacc[ntq] += (p0 + p1) + (p2 + p3);
                    uint2 u; u.x = tpk2(p0, p1); u.y = tpk2(p2, p3);
                    *(uint2*)&Pw[(16 * ntq + ml) * LDP + 16 * mts + 4 * quad] = u;
                }

            // ---- O^T += V^T * P^T (wave-private LDS round trip, no barrier) ----
#pragma unroll
            for (int ntq = 0; ntq < 4; ntq++) {
                bf16x8 pb0 = *(const bf16x8*)&Pw[(16 * ntq + ml) * LDP + quad * 8];
                bf16x8 pb1 = *(const bf16x8*)&Pw[(16 * ntq + ml) * LDP + quad * 8 + 32];
#pragma unroll
                for (int mte = 0; mte < 4; mte++) {
                    oaccT[mte][ntq] = __builtin_amdgcn_mfma_f32_16x16x32_bf16(
                        *(const bf16x8*)&vc[2 * mte], pb0, oaccT[mte][ntq], 0, 0, 0);
                    oaccT[mte][ntq] = __builtin_amdgcn_mfma_f32_16x16x32_bf16(
                        *(const bf16x8*)&vc[2 * mte + 1], pb1, oaccT[mte][ntq], 0, 0, 0);
                }
            }

            if (more) {
#pragma unroll
                for (int f = 0; f < 8; f++) { kc[f] = kn[f]; vc[f] = vn[f]; }
            }
        }

        // ---- write partials: O^T (bf16, rows=[q][e]) + l ----
#pragma unroll
        for (int mte = 0; mte < 4; mte++)
#pragma unroll
            for (int ntq = 0; ntq < 4; ntq++) {
                uint2 u;
                u.x = pk2(oaccT[mte][ntq][0], oaccT[mte][ntq][1]);
                u.y = pk2(oaccT[mte][ntq][2], oaccT[mte][ntq][3]);
                *(uint2*)&Pw[(16 * ntq + ml) * LDP + 16 * mte + 4 * quad] = u;
            }
#pragma unroll
        for (int ntq = 0; ntq < 4; ntq++)
            Lbuf[(w * 4 + quad) * 64 + 16 * ntq + ml] = lacc[ntq];

        __syncthreads();

        // ---- reduce 8 partials, normalize, store fp32 ----
        {
            const int q = tid >> 3, c = tid & 7;
            float lsum = 0.f;
#pragma unroll
            for (int i = 0; i < 4 * NW; i++) lsum += Lbuf[i * 64 + q];
            const float inv = 1.f / lsum;
            float* orow = out + (((size_t)b * LL + q0 + q) * HH + h) * EDIM;
#pragma unroll
            for (int c4 = 0; c4 < 2; c4++) {
                const int e0 = c * 8 + c4 * 4;
                float a0 = 0.f, a1 = 0.f, a2 = 0.f, a3 = 0.f;
#pragma unroll
                for (int wv = 0; wv < NW; wv++) {
                    uint2 u = *(const uint2*)&Pq[wv * 64 * LDP + q * LDP + e0];
                    a0 += bf2f(u.x & 0xffffu); a1 += bf2f(u.x >> 16);
                    a2 += bf2f(u.y & 0xffffu); a3 += bf2f(u.y >> 16);
                }
                float4 r; r.x = a0 * inv; r.y = a1 * inv; r.z = a2 * inv; r.w = a3 * inv;
                *(float4*)&orow[e0] = r;
            }
        }
    }
}

extern "C" void kernel_launch(void* const* d_in, const int* in_sizes, int n_in,
                              void* d_out, int out_size, void* d_ws, size_t ws_size,
                              hipStream_t stream)
{
    const float* qry  = (const float*)d_in[0];
    const float* key  = (const float*)d_in[1];
    const float* val  = (const float*)d_in[2];
    const float* Wang = (const float*)d_in[3];
    const float* bang = (const float*)d_in[4];
    const float* Wout = (const float*)d_in[5];
    const float* bout = (const float*)d_in[6];
    float* out = (float*)d_out;

    unsigned short* qevb = (unsigned short*)d_ws;                                             // 4 MB
    unsigned short* Kb   = (unsigned short*)((char*)d_ws + (size_t)BB * HH * EDIM * SS * 2);  // 4 MB

    (void)in_sizes; (void)n_in; (void)out_size; (void)ws_size;

    const size_t smem = (size_t)(1 + NW) * 64 * LDP * 2 + (size_t)4 * NW * 64 * 4;  // 91136 B

    qev4_kernel<<<dim3(SS / 64, HH, BB), 256, 0, stream>>>(val, key, Wang, bang, Wout, bout, qevb, Kb);
    attn7_kernel<<<dim3(NPAIR, HH, BB), 512, smem, stream>>>(qry, Kb, qevb, out);
}

// Round 13
// 137.583 us; speedup vs baseline: 1.1923x; 1.1923x over previous
//
#include <hip/hip_runtime.h>

#define NP   16
#define EDIM 64
#define HH   8
#define BB   2
#define LL   2048
#define SS   2048
#define NQT  32
#define LDP  72            // LDS row stride in bf16 (64 + 8 pad)

typedef __attribute__((ext_vector_type(8))) short bf16x8;
typedef __attribute__((ext_vector_type(4))) float f32x4;

__device__ __forceinline__ float bf2f(unsigned int u) {
    union { unsigned int i; float f; } x; x.i = u << 16; return x.f;
}
__device__ __forceinline__ unsigned short f2bf(float f) {
    union { float ff; unsigned int i; } x; x.ff = f;
    unsigned int r = x.i + 0x7fffu + ((x.i >> 16) & 1u);
    return (unsigned short)(r >> 16);
}
__device__ __forceinline__ unsigned int pk2(float a, float b) {
    return (unsigned int)f2bf(a) | ((unsigned int)f2bf(b) << 16);
}
__device__ __forceinline__ unsigned int tpk2(float a, float b) {   // truncate-pack
    union { float f; unsigned int i; } xa, xb; xa.f = a; xb.f = b;
    return (xa.i >> 16) | (xb.i & 0xffff0000u);
}

#define INV4PI 0.07957747154594767f

// ---------------------------------------------------------------------------
// Kernel 1: quantum encoding, 4 threads/token (quad shfl reduce for angles,
// redundant circuit, 16-e slice of out-GEMV). Also converts K -> Kb (bf16
// head-major) and Q -> Qb (bf16 head-major, PRE-SCALED by 0.125).
// No LDS, no barriers. 8 waves/CU.
// ---------------------------------------------------------------------------
__global__ __launch_bounds__(256)
void qev5_kernel(const float* __restrict__ values,  // [B,S,H,E]
                 const float* __restrict__ key,     // [B,S,H,E]
                 const float* __restrict__ qry,     // [B,L,H,E]
                 const float* __restrict__ Wang, const float* __restrict__ bang,
                 const float* __restrict__ Wout, const float* __restrict__ bout,
                 unsigned short* __restrict__ qevb, // [B,H,E,S]
                 unsigned short* __restrict__ Kb,   // [B,H,S,E]
                 unsigned short* __restrict__ Qb)   // [B,H,L,E] scaled
{
    const int tid   = threadIdx.x;
    const int s0    = blockIdx.x * 64;
    const int h     = blockIdx.y;
    const int b     = blockIdx.z;
    const int token = s0 + (tid >> 2);
    const int p4    = tid & 3;

    const float* vptr = values + ((size_t)(b * SS + token) * HH + h) * EDIM + p4 * 16;
    float4 vv[4];
#pragma unroll
    for (int c = 0; c < 4; c++) vv[c] = ((const float4*)vptr)[c];

    float ang[NP];
#pragma unroll
    for (int p = 0; p < NP; p++) {
        const float4* wp = (const float4*)(Wang + p * EDIM + p4 * 16);
        float a = 0.f;
#pragma unroll
        for (int c = 0; c < 4; c++) {
            float4 w = wp[c];
            a = fmaf(w.x, vv[c].x, a);
            a = fmaf(w.y, vv[c].y, a);
            a = fmaf(w.z, vv[c].z, a);
            a = fmaf(w.w, vv[c].w, a);
        }
        a += __shfl_xor(a, 1, 64);
        a += __shfl_xor(a, 2, 64);
        ang[p] = a + bang[p];
    }

    float sc[NP], cc[NP];
#pragma unroll
    for (int p = 0; p < NP; p++) {
        float u = ang[p] * INV4PI;
        sc[p] = __builtin_amdgcn_sinf(u);
        cc[p] = __builtin_amdgcn_cosf(u);
    }

    float sr[16], si[16];
#pragma unroll
    for (int i = 0; i < 16; i++) { sr[i] = 0.f; si[i] = 0.f; }
    sr[0] = 1.f;

    auto RY = [&](int w, float s, float c) {
        const int bit = 8 >> w;
#pragma unroll
        for (int i = 0; i < 16; i++) {
            if (!(i & bit)) {
                const int j = i | bit;
                float a0r = sr[i], a0i = si[i], a1r = sr[j], a1i = si[j];
                sr[i] = c * a0r - s * a1r;  si[i] = c * a0i - s * a1i;
                sr[j] = s * a0r + c * a1r;  si[j] = s * a0i + c * a1i;
            }
        }
    };
    auto CRX = [&](int cw, int tw, float s, float c) {
        const int cbit = 8 >> cw, tbit = 8 >> tw;
#pragma unroll
        for (int i = 0; i < 16; i++) {
            if ((i & cbit) && !(i & tbit)) {
                const int j = i | tbit;
                float a0r = sr[i], a0i = si[i], a1r = sr[j], a1i = si[j];
                sr[i] =  c * a0r + s * a1i;  si[i] =  c * a0i - s * a1r;
                sr[j] =  s * a0i + c * a1r;  si[j] = -s * a0r + c * a1i;
            }
        }
    };

    RY(0, sc[0], cc[0]); RY(1, sc[1], cc[1]); RY(2, sc[2], cc[2]); RY(3, sc[3], cc[3]);
    CRX(3, 0, sc[4], cc[4]); CRX(2, 3, sc[5], cc[5]); CRX(1, 2, sc[6], cc[6]); CRX(0, 1, sc[7], cc[7]);
    RY(0, sc[8], cc[8]); RY(1, sc[9], cc[9]); RY(2, sc[10], cc[10]); RY(3, sc[11], cc[11]);
    CRX(3, 2, sc[12], cc[12]); CRX(0, 3, sc[13], cc[13]); CRX(1, 0, sc[14], cc[14]); CRX(2, 1, sc[15], cc[15]);

    float meas[12];
#pragma unroll
    for (int w = 0; w < 4; w++) {
        const int bit = 8 >> w;
        float pr = 0.f, pi = 0.f, z = 0.f;
#pragma unroll
        for (int i = 0; i < 16; i++) {
            if (!(i & bit)) {
                const int j = i | bit;
                pr += sr[i] * sr[j] + si[i] * si[j];
                pi += sr[i] * si[j] - si[i] * sr[j];
                z  += sr[i] * sr[i] + si[i] * si[i] - sr[j] * sr[j] - si[j] * si[j];
            }
        }
        meas[w] = 2.f * pr; meas[4 + w] = 2.f * pi; meas[8 + w] = z;
    }

    unsigned short* ob = qevb + ((size_t)(b * HH + h) * EDIM) * SS + token;
    const float4* bo4 = (const float4*)(bout + p4 * 16);
    float4 bo[4] = { bo4[0], bo4[1], bo4[2], bo4[3] };
#pragma unroll
    for (int j = 0; j < 16; j++) {
        const int e = p4 * 16 + j;
        const float4* wr = (const float4*)(Wout + e * 12);
        float4 w0 = wr[0], w1 = wr[1], w2 = wr[2];
        float a = ((const float*)bo)[j];
        a = fmaf(meas[0], w0.x, a);  a = fmaf(meas[1],  w0.y, a);
        a = fmaf(meas[2], w0.z, a);  a = fmaf(meas[3],  w0.w, a);
        a = fmaf(meas[4], w1.x, a);  a = fmaf(meas[5],  w1.y, a);
        a = fmaf(meas[6], w1.z, a);  a = fmaf(meas[7],  w1.w, a);
        a = fmaf(meas[8], w2.x, a);  a = fmaf(meas[9],  w2.y, a);
        a = fmaf(meas[10], w2.z, a); a = fmaf(meas[11], w2.w, a);
        ob[(size_t)e * SS] = f2bf(a);
    }

    // ---- K conversion (coalesced 512B writes) ----
    const float* ks = key + ((size_t)b * SS * HH + h) * EDIM;
    unsigned short* kd = Kb + ((size_t)(b * HH + h) * SS + s0) * EDIM;
#pragma unroll
    for (int i = 0; i < 4; i++) {
        const int u   = i * 256 + tid;
        const int row = u >> 4;
        const int ch  = u & 15;
        float4 v = *(const float4*)(ks + (size_t)(s0 + row) * HH * EDIM + ch * 4);
        uint2 w2; w2.x = pk2(v.x, v.y); w2.y = pk2(v.z, v.w);
        *(uint2*)&kd[row * EDIM + ch * 4] = w2;
    }

    // ---- Q conversion, PRE-SCALED by softmax scale 1/8 ----
    const float* qs_ = qry + ((size_t)b * LL * HH + h) * EDIM;
    unsigned short* qd = Qb + ((size_t)(b * HH + h) * LL + s0) * EDIM;
#pragma unroll
    for (int i = 0; i < 4; i++) {
        const int u   = i * 256 + tid;
        const int row = u >> 4;
        const int ch  = u & 15;
        float4 v = *(const float4*)(qs_ + (size_t)(s0 + row) * HH * EDIM + ch * 4);
        uint2 w2; w2.x = pk2(v.x * 0.125f, v.y * 0.125f); w2.y = pk2(v.z * 0.125f, v.w * 0.125f);
        *(uint2*)&qd[row * EDIM + ch * 4] = w2;
    }
}

// ---------------------------------------------------------------------------
// Kernel 2: wave-owned-tile MFMA attention, one q-tile per block, 4 waves.
// Grid (32,H,B) = 512 blocks -> 2 blocks/CU; batch-complement swizzle
// qt = b ? 31-bx : bx pairs long+short tiles per CU. Rotating single K/V
// register buffer (reload into same regs AFTER consumption -> no spills).
// Q B-fragments direct from pre-scaled bf16 global. Barrier-free K-loop.
// ---------------------------------------------------------------------------
__global__ __launch_bounds__(256, 1)
void attn8_kernel(const unsigned short* __restrict__ Qb,    // [B,H,L,E] bf16 (x0.125)
                  const unsigned short* __restrict__ Kb,    // [B,H,S,E] bf16
                  const unsigned short* __restrict__ Vb,    // [B,H,E,S] bf16
                  float* __restrict__ out)                  // [B,L,H,E] fp32
{
    __shared__ unsigned short Pq[4][64 * LDP];   // per-wave P[q][s] / O-partial[q][e]
    __shared__ float Lbuf[16 * 64];

    const int tid  = threadIdx.x;
    const int bx   = blockIdx.x;     // 0..31
    const int h    = blockIdx.y;
    const int b    = blockIdx.z;
    const int qt   = b ? (NQT - 1 - bx) : bx;    // CU-pairing swizzle
    const int q0   = qt * 64;
    const int w    = tid >> 6;
    const int lane = tid & 63;
    const int ml   = lane & 15;
    const int quad = lane >> 4;

    const unsigned short* kbase = Kb + (size_t)(b * HH + h) * SS * EDIM;
    const unsigned short* vbase = Vb + (size_t)(b * HH + h) * EDIM * SS;
    const unsigned short* qbase = Qb + (size_t)(b * HH + h) * LL * EDIM;
    unsigned short* Pw = &Pq[w][0];

    // Q B-fragments (rows = q) direct from global, loop-invariant
    bf16x8 bq[4][2];
#pragma unroll
    for (int ntq = 0; ntq < 4; ntq++) {
        const unsigned short* qr = qbase + (size_t)(q0 + 16 * ntq + ml) * EDIM + quad * 8;
        bq[ntq][0] = *(const bf16x8*)qr;
        bq[ntq][1] = *(const bf16x8*)(qr + 32);
    }

    f32x4 oaccT[4][4];    // [mte][ntq]: O^T[e][q]
    float lacc[4] = {0.f, 0.f, 0.f, 0.f};
#pragma unroll
    for (int i = 0; i < 4; i++)
#pragma unroll
        for (int j = 0; j < 4; j++) oaccT[i][j] = (f32x4)(0.f);

    int t = w;
    uint4 kc[8], vc[8];
    if (t <= qt) {
#pragma unroll
        for (int f = 0; f < 8; f++) {
            const int mt = f >> 1, hf = f & 1;
            kc[f] = *(const uint4*)(kbase + (size_t)(t * 64 + 16 * mt + ml) * EDIM + quad * 8 + 32 * hf);
            vc[f] = *(const uint4*)(vbase + (size_t)(16 * mt + ml) * SS + t * 64 + quad * 8 + 32 * hf);
        }
    }

    for (; t <= qt; t += 4) {
        const bool diag = (t == qt);
        const bool more = (t + 4 <= qt);

        // ---- S^T = K*Q^T, exp, pack into Pw[q][s] (consumes kc) ----
#pragma unroll
        for (int mts = 0; mts < 4; mts++)
#pragma unroll
            for (int ntq = 0; ntq < 4; ntq++) {
                f32x4 s = __builtin_amdgcn_mfma_f32_16x16x32_bf16(
                    *(const bf16x8*)&kc[2 * mts], bq[ntq][0], (f32x4)(0.f), 0, 0, 0);
                s = __builtin_amdgcn_mfma_f32_16x16x32_bf16(
                    *(const bf16x8*)&kc[2 * mts + 1], bq[ntq][1], s, 0, 0, 0);
                float p0 = __expf(s[0]), p1 = __expf(s[1]), p2 = __expf(s[2]), p3 = __expf(s[3]);
                if (diag) {
                    const int sbase = 16 * mts + 4 * quad, qcol = 16 * ntq + ml;
                    if (sbase + 0 > qcol) p0 = 0.f;
                    if (sbase + 1 > qcol) p1 = 0.f;
                    if (sbase + 2 > qcol) p2 = 0.f;
                    if (sbase + 3 > qcol) p3 = 0.f;
                }
                lacc[ntq] += (p0 + p1) + (p2 + p3);
                uint2 u; u.x = tpk2(p0, p1); u.y = tpk2(p2, p3);
                *(uint2*)&Pw[(16 * ntq + ml) * LDP + 16 * mts + 4 * quad] = u;
            }

        // ---- kc consumed: reload for t+4 into the SAME registers ----
        if (more) {
#pragma unroll
            for (int f = 0; f < 8; f++) {
                const int mt = f >> 1, hf = f & 1;
                kc[f] = *(const uint4*)(kbase + (size_t)((t + 4) * 64 + 16 * mt + ml) * EDIM + quad * 8 + 32 * hf);
            }
        }

        // ---- O^T += V^T * P^T (wave-private LDS round trip; consumes vc) ----
#pragma unroll
        for (int ntq = 0; ntq < 4; ntq++) {
            bf16x8 pb0 = *(const bf16x8*)&Pw[(16 * ntq + ml) * LDP + quad * 8];
            bf16x8 pb1 = *(const bf16x8*)&Pw[(16 * ntq + ml) * LDP + quad * 8 + 32];
#pragma unroll
            for (int mte = 0; mte < 4; mte++) {
                oaccT[mte][ntq] = __builtin_amdgcn_mfma_f32_16x16x32_bf16(
                    *(const bf16x8*)&vc[2 * mte], pb0, oaccT[mte][ntq], 0, 0, 0);
                oaccT[mte][ntq] = __builtin_amdgcn_mfma_f32_16x16x32_bf16(
                    *(const bf16x8*)&vc[2 * mte + 1], pb1, oaccT[mte][ntq], 0, 0, 0);
            }
        }

        // ---- vc consumed: reload for t+4 ----
        if (more) {
#pragma unroll
            for (int f = 0; f < 8; f++) {
                const int mt = f >> 1, hf = f & 1;
                vc[f] = *(const uint4*)(vbase + (size_t)(16 * mt + ml) * SS + (t + 4) * 64 + quad * 8 + 32 * hf);
            }
        }
    }

    // ---- write partials: O^T (bf16, rows=[q][e]) + l ----
#pragma unroll
    for (int mte = 0; mte < 4; mte++)
#pragma unroll
        for (int ntq = 0; ntq < 4; ntq++) {
            uint2 u;
            u.x = pk2(oaccT[mte][ntq][0], oaccT[mte][ntq][1]);
            u.y = pk2(oaccT[mte][ntq][2], oaccT[mte][ntq][3]);
            *(uint2*)&Pw[(16 * ntq + ml) * LDP + 16 * mte + 4 * quad] = u;
        }
#pragma unroll
    for (int ntq = 0; ntq < 4; ntq++)
        Lbuf[(w * 4 + quad) * 64 + 16 * ntq + ml] = lacc[ntq];

    __syncthreads();

    // ---- reduce 4 partials, normalize, store fp32 float4 ----
    {
        const int q = tid >> 2, c = tid & 3;
        float lsum = 0.f;
#pragma unroll
        for (int i = 0; i < 16; i++) lsum += Lbuf[i * 64 + q];
        const float inv = 1.f / lsum;
        float* orow = out + (((size_t)b * LL + q0 + q) * HH + h) * EDIM;
#pragma unroll
        for (int c4 = 0; c4 < 4; c4++) {
            const int e0 = c * 16 + c4 * 4;
            float a0 = 0.f, a1 = 0.f, a2 = 0.f, a3 = 0.f;
#pragma unroll
            for (int wv = 0; wv < 4; wv++) {
                uint2 u = *(const uint2*)&Pq[wv][q * LDP + e0];
                a0 += bf2f(u.x & 0xffffu); a1 += bf2f(u.x >> 16);
                a2 += bf2f(u.y & 0xffffu); a3 += bf2f(u.y >> 16);
            }
            float4 r; r.x = a0 * inv; r.y = a1 * inv; r.z = a2 * inv; r.w = a3 * inv;
            *(float4*)&orow[e0] = r;
        }
    }
}

extern "C" void kernel_launch(void* const* d_in, const int* in_sizes, int n_in,
                              void* d_out, int out_size, void* d_ws, size_t ws_size,
                              hipStream_t stream)
{
    const float* qry  = (const float*)d_in[0];
    const float* key  = (const float*)d_in[1];
    const float* val  = (const float*)d_in[2];
    const float* Wang = (const float*)d_in[3];
    const float* bang = (const float*)d_in[4];
    const float* Wout = (const float*)d_in[5];
    const float* bout = (const float*)d_in[6];
    float* out = (float*)d_out;

    const size_t seg = (size_t)BB * HH * EDIM * SS * 2;   // 4 MB per bf16 tensor
    unsigned short* qevb = (unsigned short*)d_ws;
    unsigned short* Kb   = (unsigned short*)((char*)d_ws + seg);
    unsigned short* Qb   = (unsigned short*)((char*)d_ws + 2 * seg);

    (void)in_sizes; (void)n_in; (void)out_size; (void)ws_size;

    qev5_kernel<<<dim3(SS / 64, HH, BB), 256, 0, stream>>>(val, key, qry, Wang, bang, Wout, bout, qevb, Kb, Qb);
    attn8_kernel<<<dim3(NQT, HH, BB), 256, 0, stream>>>(Qb, Kb, qevb, out);
}

// Round 14
// 118.807 us; speedup vs baseline: 1.3808x; 1.1580x over previous
//
#include <hip/hip_runtime.h>

#define NP   16
#define EDIM 64
#define HH   8
#define BB   2
#define LL   2048
#define SS   2048
#define NQT  32
#define NPAIR 16
#define LDP  72            // LDS row stride in bf16 (64 + 8 pad)

typedef __attribute__((ext_vector_type(8))) short bf16x8;
typedef __attribute__((ext_vector_type(4))) float f32x4;

__device__ __forceinline__ float bf2f(unsigned int u) {
    union { unsigned int i; float f; } x; x.i = u << 16; return x.f;
}
__device__ __forceinline__ unsigned short f2bf(float f) {
    union { float ff; unsigned int i; } x; x.ff = f;
    unsigned int r = x.i + 0x7fffu + ((x.i >> 16) & 1u);
    return (unsigned short)(r >> 16);
}
__device__ __forceinline__ unsigned int pk2(float a, float b) {
    return (unsigned int)f2bf(a) | ((unsigned int)f2bf(b) << 16);
}
__device__ __forceinline__ unsigned int tpk2(float a, float b) {   // truncate-pack
    union { float f; unsigned int i; } xa, xb; xa.f = a; xb.f = b;
    return (xa.i >> 16) | (xb.i & 0xffff0000u);
}

// 16 fp32 (global) -> 16 bf16 (LDS), scaled
__device__ __forceinline__ void stage16s(const float* __restrict__ g, unsigned short* l, float sc) {
    const float4* gp = (const float4*)g;
    float4 v0 = gp[0], v1 = gp[1], v2 = gp[2], v3 = gp[3];
    uint4 w0, w1;
    w0.x = pk2(v0.x * sc, v0.y * sc); w0.y = pk2(v0.z * sc, v0.w * sc);
    w0.z = pk2(v1.x * sc, v1.y * sc); w0.w = pk2(v1.z * sc, v1.w * sc);
    w1.x = pk2(v2.x * sc, v2.y * sc); w1.y = pk2(v2.z * sc, v2.w * sc);
    w1.z = pk2(v3.x * sc, v3.y * sc); w1.w = pk2(v3.z * sc, v3.w * sc);
    ((uint4*)l)[0] = w0; ((uint4*)l)[1] = w1;
}

#define INV4PI 0.07957747154594767f

// ---------------------------------------------------------------------------
// Kernel 1: fused quantum-encoding + K-conversion. Grid (64, H, B), 64 thr.
//   bx <  32 : qev-lite -- one thread per token, hoisted value loads, batch
//              sincos, circuit, transposed bf16 qevb store (r11-proven body).
//   bx >= 32 : pure K-convert block -- ALL 16 float4 loads hoisted into
//              registers (no circuit state competing for VGPRs), then
//              convert + 512B-coalesced stores.
// The two block types are independent and co-scheduled -> the conversion
// streams while qev-lite's latency stalls are filled. No Qb (attn stages Q).
// ---------------------------------------------------------------------------
__global__ __launch_bounds__(64)
void qev6_kernel(const float* __restrict__ values,  // [B,S,H,E]
                 const float* __restrict__ key,     // [B,S,H,E]
                 const float* __restrict__ Wang, const float* __restrict__ bang,
                 const float* __restrict__ Wout, const float* __restrict__ bout,
                 unsigned short* __restrict__ qevb, // [B,H,E,S]
                 unsigned short* __restrict__ Kb)   // [B,H,S,E]
{
    const int tid = threadIdx.x;
    const int bx  = blockIdx.x;
    const int h   = blockIdx.y;
    const int b   = blockIdx.z;

    if (bx >= 32) {
        // ---------------- K-conversion block ----------------
        const int s0 = (bx - 32) * 64;
        const float* ks = key + ((size_t)b * SS * HH + h) * EDIM;
        unsigned short* kd = Kb + ((size_t)(b * HH + h) * SS + s0) * EDIM;
        float4 v[16];
#pragma unroll
        for (int i = 0; i < 16; i++) {
            const int u = i * 64 + tid;
            const int row = u >> 4, ch = u & 15;
            v[i] = *(const float4*)(ks + (size_t)(s0 + row) * HH * EDIM + ch * 4);
        }
#pragma unroll
        for (int i = 0; i < 16; i++) {
            const int u = i * 64 + tid;
            const int row = u >> 4, ch = u & 15;
            uint2 w2; w2.x = pk2(v[i].x, v[i].y); w2.y = pk2(v[i].z, v[i].w);
            *(uint2*)&kd[row * EDIM + ch * 4] = w2;
        }
        return;
    }

    // ---------------- qev-lite block ----------------
    __shared__ float sW[NP * EDIM];
    __shared__ float sWo[EDIM * 12];
    __shared__ float sba[NP];
    __shared__ float sbo[EDIM];

    const int s0 = bx * 64;

#pragma unroll
    for (int i = 0; i < 4; i++) ((float4*)sW)[i * 64 + tid] = ((const float4*)Wang)[i * 64 + tid];
#pragma unroll
    for (int i = 0; i < 3; i++) ((float4*)sWo)[i * 64 + tid] = ((const float4*)Wout)[i * 64 + tid];
    if (tid < NP) sba[tid] = bang[tid];
    sbo[tid] = bout[tid];
    __syncthreads();

    // hoisted value loads (16 independent float4s)
    const float* vptr = values + ((size_t)(b * SS + s0 + tid) * HH + h) * EDIM;
    float4 vv[16];
#pragma unroll
    for (int c = 0; c < 16; c++) vv[c] = ((const float4*)vptr)[c];

    float ang[NP];
#pragma unroll
    for (int p = 0; p < NP; p++) ang[p] = sba[p];
#pragma unroll
    for (int c = 0; c < 16; c++) {
#pragma unroll
        for (int p = 0; p < NP; p++) {
            float a = ang[p];
            a = fmaf(sW[p * EDIM + c * 4 + 0], vv[c].x, a);
            a = fmaf(sW[p * EDIM + c * 4 + 1], vv[c].y, a);
            a = fmaf(sW[p * EDIM + c * 4 + 2], vv[c].z, a);
            a = fmaf(sW[p * EDIM + c * 4 + 3], vv[c].w, a);
            ang[p] = a;
        }
    }

    float sc[NP], cc[NP];
#pragma unroll
    for (int p = 0; p < NP; p++) {
        float u = ang[p] * INV4PI;
        sc[p] = __builtin_amdgcn_sinf(u);
        cc[p] = __builtin_amdgcn_cosf(u);
    }

    float sr[16], si[16];
#pragma unroll
    for (int i = 0; i < 16; i++) { sr[i] = 0.f; si[i] = 0.f; }
    sr[0] = 1.f;

    auto RY = [&](int w, float s, float c) {
        const int bit = 8 >> w;
#pragma unroll
        for (int i = 0; i < 16; i++) {
            if (!(i & bit)) {
                const int j = i | bit;
                float a0r = sr[i], a0i = si[i], a1r = sr[j], a1i = si[j];
                sr[i] = c * a0r - s * a1r;  si[i] = c * a0i - s * a1i;
                sr[j] = s * a0r + c * a1r;  si[j] = s * a0i + c * a1i;
            }
        }
    };
    auto CRX = [&](int cw, int tw, float s, float c) {
        const int cbit = 8 >> cw, tbit = 8 >> tw;
#pragma unroll
        for (int i = 0; i < 16; i++) {
            if ((i & cbit) && !(i & tbit)) {
                const int j = i | tbit;
                float a0r = sr[i], a0i = si[i], a1r = sr[j], a1i = si[j];
                sr[i] =  c * a0r + s * a1i;  si[i] =  c * a0i - s * a1r;
                sr[j] =  s * a0i + c * a1r;  si[j] = -s * a0r + c * a1i;
            }
        }
    };

    RY(0, sc[0], cc[0]); RY(1, sc[1], cc[1]); RY(2, sc[2], cc[2]); RY(3, sc[3], cc[3]);
    CRX(3, 0, sc[4], cc[4]); CRX(2, 3, sc[5], cc[5]); CRX(1, 2, sc[6], cc[6]); CRX(0, 1, sc[7], cc[7]);
    RY(0, sc[8], cc[8]); RY(1, sc[9], cc[9]); RY(2, sc[10], cc[10]); RY(3, sc[11], cc[11]);
    CRX(3, 2, sc[12], cc[12]); CRX(0, 3, sc[13], cc[13]); CRX(1, 0, sc[14], cc[14]); CRX(2, 1, sc[15], cc[15]);

    float meas[12];
#pragma unroll
    for (int w = 0; w < 4; w++) {
        const int bit = 8 >> w;
        float pr = 0.f, pi = 0.f, z = 0.f;
#pragma unroll
        for (int i = 0; i < 16; i++) {
            if (!(i & bit)) {
                const int j = i | bit;
                pr += sr[i] * sr[j] + si[i] * si[j];
                pi += sr[i] * si[j] - si[i] * sr[j];
                z  += sr[i] * sr[i] + si[i] * si[i] - sr[j] * sr[j] - si[j] * si[j];
            }
        }
        meas[w] = 2.f * pr; meas[4 + w] = 2.f * pi; meas[8 + w] = z;
    }

    unsigned short* ob = qevb + ((size_t)(b * HH + h) * EDIM) * SS + s0 + tid;
#pragma unroll
    for (int eb = 0; eb < 4; eb++) {
        float acc[16];
#pragma unroll
        for (int j = 0; j < 16; j++) acc[j] = sbo[eb * 16 + j];
#pragma unroll
        for (int mm = 0; mm < 12; mm++)
#pragma unroll
            for (int j = 0; j < 16; j++)
                acc[j] = fmaf(meas[mm], sWo[(eb * 16 + j) * 12 + mm], acc[j]);
#pragma unroll
        for (int j = 0; j < 16; j++)
            ob[(size_t)(eb * 16 + j) * SS] = f2bf(acc[j]);
    }
}

// ---------------------------------------------------------------------------
// Kernel 2: wave-owned-tile MFMA attention (r11-proven attn6, verbatim).
// Block = 4 waves, one causal pair (qt = bx, 31-bx). Wave w owns tiles
// t === w (mod 4), all 64 q-rows (no-max softmax partials are exactly
// additive). Barrier-free K-loop, full-tile-distance register prefetch.
// ---------------------------------------------------------------------------
__global__ __launch_bounds__(256, 1)
void attn6_kernel(const float* __restrict__ qry,            // [B,L,H,E] fp32
                  const unsigned short* __restrict__ Kb,    // [B,H,S,E] bf16
                  const unsigned short* __restrict__ Vb,    // [B,H,E,S] bf16
                  float* __restrict__ out)                  // [B,L,H,E] fp32
{
    __shared__ unsigned short Qs[64 * LDP];
    __shared__ unsigned short Pq[4][64 * LDP];   // per-wave P[q][s] / O-partial[q][e]
    __shared__ float Lbuf[16 * 64];

    const int tid  = threadIdx.x;
    const int bx   = blockIdx.x;
    const int h    = blockIdx.y;
    const int b    = blockIdx.z;
    const int w    = tid >> 6;
    const int lane = tid & 63;
    const int ml   = lane & 15;
    const int quad = lane >> 4;
    const int srow = tid >> 2;
    const int sch  = tid & 3;

    const unsigned short* kbase = Kb + (size_t)(b * HH + h) * SS * EDIM;
    const unsigned short* vbase = Vb + (size_t)(b * HH + h) * EDIM * SS;
    unsigned short* Pw = &Pq[w][0];

    for (int pass = 0; pass < 2; ++pass) {
        const int qt = pass ? (NQT - 1 - bx) : bx;
        const int q0 = qt * 64;

        __syncthreads();   // prev pass readers done with Qs/Pq
        stage16s(qry + (((size_t)b * LL + q0 + srow) * HH + h) * EDIM + sch * 16,
                 &Qs[srow * LDP + sch * 16], 0.125f);
        __syncthreads();

        // Q B-fragments (rows = q), loop-invariant
        bf16x8 bq[4][2];
#pragma unroll
        for (int ntq = 0; ntq < 4; ntq++) {
            bq[ntq][0] = *(const bf16x8*)&Qs[(16 * ntq + ml) * LDP + quad * 8];
            bq[ntq][1] = *(const bf16x8*)&Qs[(16 * ntq + ml) * LDP + quad * 8 + 32];
        }

        f32x4 oaccT[4][4];    // [mte][ntq]: O^T[e][q]
        float lacc[4] = {0.f, 0.f, 0.f, 0.f};
#pragma unroll
        for (int i = 0; i < 4; i++)
#pragma unroll
            for (int j = 0; j < 4; j++) oaccT[i][j] = (f32x4)(0.f);

        int t = w;
        uint4 kc[8], vc[8];
        if (t <= qt) {
#pragma unroll
            for (int f = 0; f < 8; f++) {
                const int mt = f >> 1, hf = f & 1;
                kc[f] = *(const uint4*)(kbase + (size_t)(t * 64 + 16 * mt + ml) * EDIM + quad * 8 + 32 * hf);
                vc[f] = *(const uint4*)(vbase + (size_t)(16 * mt + ml) * SS + t * 64 + quad * 8 + 32 * hf);
            }
        }

        for (; t <= qt; t += 4) {
            uint4 kn[8], vn[8];
            const bool more = (t + 4 <= qt);
            if (more) {
#pragma unroll
                for (int f = 0; f < 8; f++) {
                    const int mt = f >> 1, hf = f & 1;
                    kn[f] = *(const uint4*)(kbase + (size_t)((t + 4) * 64 + 16 * mt + ml) * EDIM + quad * 8 + 32 * hf);
                    vn[f] = *(const uint4*)(vbase + (size_t)(16 * mt + ml) * SS + (t + 4) * 64 + quad * 8 + 32 * hf);
                }
            }
            const bool diag = (t == qt);

            // ---- S^T = K*Q^T, exp, pack into Pw[q][s] ----
#pragma unroll
            for (int mts = 0; mts < 4; mts++)
#pragma unroll
                for (int ntq = 0; ntq < 4; ntq++) {
                    f32x4 s = __builtin_amdgcn_mfma_f32_16x16x32_bf16(
                        *(const bf16x8*)&kc[2 * mts], bq[ntq][0], (f32x4)(0.f), 0, 0, 0);
                    s = __builtin_amdgcn_mfma_f32_16x16x32_bf16(
                        *(const bf16x8*)&kc[2 * mts + 1], bq[ntq][1], s, 0, 0, 0);
                    float p0 = __expf(s[0]), p1 = __expf(s[1]), p2 = __expf(s[2]), p3 = __expf(s[3]);
                    if (diag) {
                        const int sbase = 16 * mts + 4 * quad, qcol = 16 * ntq + ml;
                        if (sbase + 0 > qcol) p0 = 0.f;
                        if (sbase + 1 > qcol) p1 = 0.f;
                        if (sbase + 2 > qcol) p2 = 0.f;
                        if (sbase + 3 > qcol) p3 = 0.f;
                    }
                    lacc[ntq] += (p0 + p1) + (p2 + p3);
                    uint2 u; u.x = tpk2(p0, p1); u.y = tpk2(p2, p3);
                    *(uint2*)&Pw[(16 * ntq + ml) * LDP + 16 * mts + 4 * quad] = u;
                }

            // ---- O^T += V^T * P^T (wave-private LDS round trip, no barrier) ----
#pragma unroll
            for (int ntq = 0; ntq < 4; ntq++) {
                bf16x8 pb0 = *(const bf16x8*)&Pw[(16 * ntq + ml) * LDP + quad * 8];
                bf16x8 pb1 = *(const bf16x8*)&Pw[(16 * ntq + ml) * LDP + quad * 8 + 32];
#pragma unroll
                for (int mte = 0; mte < 4; mte++) {
                    oaccT[mte][ntq] = __builtin_amdgcn_mfma_f32_16x16x32_bf16(
                        *(const bf16x8*)&vc[2 * mte], pb0, oaccT[mte][ntq], 0, 0, 0);
                    oaccT[mte][ntq] = __builtin_amdgcn_mfma_f32_16x16x32_bf16(
                        *(const bf16x8*)&vc[2 * mte + 1], pb1, oaccT[mte][ntq], 0, 0, 0);
                }
            }

            if (more) {
#pragma unroll
                for (int f = 0; f < 8; f++) { kc[f] = kn[f]; vc[f] = vn[f]; }
            }
        }

        // ---- write partials: O^T (bf16, rows=[q][e]) + l ----
#pragma unroll
        for (int mte = 0; mte < 4; mte++)
#pragma unroll
            for (int ntq = 0; ntq < 4; ntq++) {
                uint2 u;
                u.x = pk2(oaccT[mte][ntq][0], oaccT[mte][ntq][1]);
                u.y = pk2(oaccT[mte][ntq][2], oaccT[mte][ntq][3]);
                *(uint2*)&Pw[(16 * ntq + ml) * LDP + 16 * mte + 4 * quad] = u;
            }
#pragma unroll
        for (int ntq = 0; ntq < 4; ntq++)
            Lbuf[(w * 4 + quad) * 64 + 16 * ntq + ml] = lacc[ntq];

        __syncthreads();

        // ---- reduce 4 partials, normalize, store fp32 float4 ----
        {
            const int q = tid >> 2, c = tid & 3;
            float lsum = 0.f;
#pragma unroll
            for (int i = 0; i < 16; i++) lsum += Lbuf[i * 64 + q];
            const float inv = 1.f / lsum;
            float* orow = out + (((size_t)b * LL + q0 + q) * HH + h) * EDIM;
#pragma unroll
            for (int c4 = 0; c4 < 4; c4++) {
                const int e0 = c * 16 + c4 * 4;
                float a0 = 0.f, a1 = 0.f, a2 = 0.f, a3 = 0.f;
#pragma unroll
                for (int wv = 0; wv < 4; wv++) {
                    uint2 u = *(const uint2*)&Pq[wv][q * LDP + e0];
                    a0 += bf2f(u.x & 0xffffu); a1 += bf2f(u.x >> 16);
                    a2 += bf2f(u.y & 0xffffu); a3 += bf2f(u.y >> 16);
                }
                float4 r; r.x = a0 * inv; r.y = a1 * inv; r.z = a2 * inv; r.w = a3 * inv;
                *(float4*)&orow[e0] = r;
            }
        }
    }
}

extern "C" void kernel_launch(void* const* d_in, const int* in_sizes, int n_in,
                              void* d_out, int out_size, void* d_ws, size_t ws_size,
                              hipStream_t stream)
{
    const float* qry  = (const float*)d_in[0];
    const float* key  = (const float*)d_in[1];
    const float* val  = (const float*)d_in[2];
    const float* Wang = (const float*)d_in[3];
    const float* bang = (const float*)d_in[4];
    const float* Wout = (const float*)d_in[5];
    const float* bout = (const float*)d_in[6];
    float* out = (float*)d_out;

    const size_t seg = (size_t)BB * HH * EDIM * SS * 2;   // 4 MB per bf16 tensor
    unsigned short* qevb = (unsigned short*)d_ws;
    unsigned short* Kb   = (unsigned short*)((char*)d_ws + seg);

    (void)in_sizes; (void)n_in; (void)out_size; (void)ws_size;

    qev6_kernel<<<dim3(64, HH, BB), 64, 0, stream>>>(val, key, Wang, bang, Wout, bout, qevb, Kb);
    attn6_kernel<<<dim3(NPAIR, HH, BB), 256, 0, stream>>>(qry, Kb, qevb, out);
}